// Round 8
// baseline (558.142 us; speedup 1.0000x reference)
//
#include <hip/hip_runtime.h>
#include <math.h>

// ---- problem constants ----
#define TB        256           // threads per block = 4 waves (compute kernel)
#define POSB      64            // positions per block (1 per lane)
#define GROUPS    4             // K-split: wave g scans codes [g*KPG,(g+1)*KPG)
#define KPG       128           // codes per group
#define NPOS      131072        // B*H*W positions
#define KCODES    512
#define DIM       64
#define HW        4096          // H*W
#define LOSS_OFF  8388608ull
#define ENC_OFF   8388609ull    // encodings: 67108864 dwords, ends at 75497473
#define PERP_OFF  75497473ull
#define ENC_LEN   67108864ull

__device__ __forceinline__ float tree8(float r0, float r1, float r2, float r3,
                                       float r4, float r5, float r6, float r7) {
    // numpy pairwise combine: ((r0+r1)+(r2+r3)) + ((r4+r5)+(r6+r7))
    return __fadd_rn(__fadd_rn(__fadd_rn(r0, r1), __fadd_rn(r2, r3)),
                     __fadd_rn(__fadd_rn(r4, r5), __fadd_rn(r6, r7)));
}

// Prep: ww[k] = sum(w[k]^2) in numpy pairwise order; zero counts + loss accumulator.
extern "C" __global__ __launch_bounds__(512)
void vq_prep(const float* __restrict__ w, float* __restrict__ ww,
             int* __restrict__ counts, float* __restrict__ lossAcc)
{
    const int k = threadIdx.x;                 // 512 threads
    const float* wk = w + k * DIM;
    float r[8];
    #pragma unroll
    for (int i = 0; i < 8; ++i) {
        #pragma unroll
        for (int j = 0; j < 8; ++j) {
            float v = wk[i * 8 + j];
            float pp = __fmul_rn(v, v);
            r[j] = (i == 0) ? pp : __fadd_rn(r[j], pp);
        }
    }
    ww[k] = tree8(r[0], r[1], r[2], r[3], r[4], r[5], r[6], r[7]);
    counts[k] = 0;
    if (k == 0) *lossAcc = 0.0f;
}

// Kernel A: pure zero-fill of the encodings region, rocclr-fill shape
// (8192 blocks x 256 thr x 8 float4, block-contiguous -> coalesced).
// Region starts at odd dword ENC_OFF: 3 head dwords + 16777215 float4 + 1 tail.
extern "C" __global__ __launch_bounds__(256)
void vq_fill(float* __restrict__ out)
{
    const float4 zero4 = make_float4(0.0f, 0.0f, 0.0f, 0.0f);
    float4* dst = reinterpret_cast<float4*>(out + ENC_OFF + 3);   // 16B-aligned
    const size_t base = (size_t)blockIdx.x * (256 * 8) + threadIdx.x;
    #pragma unroll
    for (int i = 0; i < 8; ++i) {
        const size_t m = base + (size_t)i * 256;
        if (m < 16777215ull) dst[m] = zero4;
    }
    if (blockIdx.x == 0 && threadIdx.x < 4) {
        // head dwords ENC_OFF..ENC_OFF+2 and tail dword ENC_OFF+ENC_LEN-1
        const size_t d = (threadIdx.x < 3) ? (ENC_OFF + threadIdx.x)
                                           : (ENC_OFF + ENC_LEN - 1);
        out[d] = 0.0f;
    }
}

// Kernel B, R8: R7 scan + amdgpu_waves_per_eu(4,4).
// KEY COMPILER RULE (R1/R2/R5/R6/R7 evidence): the VGPR budget is set by the
// MAX of waves_per_eu — (4,8) budgeted 64 and spilled x2 (VGPR=56, 207us);
// (2,4)/(4,4) budget 128 which fits x2(64)+s[8]+addressing (~100).
// 4 waves/EU: per-iter wall = s_load(4xdwordx16) ~260cyc wait + 154cyc FMA;
// 4 waves' VALU demand 616cyc > 420cyc wall -> SMEM latency hidden.
extern "C" __global__ __launch_bounds__(TB)
__attribute__((amdgpu_waves_per_eu(4, 4)))
void vq_scan(const float* __restrict__ x, const float* __restrict__ w,
             const float* __restrict__ ww, float* __restrict__ out,
             int* __restrict__ counts, float* __restrict__ lossAcc)
{
    __shared__ float cdist[GROUPS][POSB];
    __shared__ int   ckidx[GROUPS][POSB];
    __shared__ int   hcount[KCODES];

    const int tid = threadIdx.x;
    const int l   = tid & 63;                                  // lane = position slot
    const int g   = __builtin_amdgcn_readfirstlane(tid >> 6);  // wave id, uniform
    const int n   = blockIdx.x * POSB + l;                     // position (64|4096: one b per block)
    const int b   = n >> 12;
    const int hw  = n & 4095;

    hcount[tid]      = 0;
    hcount[tid + TB] = 0;

    // ---- prologue: x into VGPRs (channel stride HW) as 16 float4 of 2x, and
    // A = sum(x^2) replicating numpy pairwise_sum(64): r[j] over i ascending,
    // chunk c -> (i = c>>1, j = (c&1)*4+e).
    const float* xp = x + ((size_t)b * DIM) * HW + hw;
    float4 x2[16];
    float r[8];
    #pragma unroll
    for (int c = 0; c < 16; ++c) {
        float v0 = xp[(size_t)(4 * c + 0) * HW];
        float v1 = xp[(size_t)(4 * c + 1) * HW];
        float v2 = xp[(size_t)(4 * c + 2) * HW];
        float v3 = xp[(size_t)(4 * c + 3) * HW];
        x2[c].x = v0 + v0; x2[c].y = v1 + v1;       // exact doubling
        x2[c].z = v2 + v2; x2[c].w = v3 + v3;
        const int j = (c & 1) * 4;
        float p0 = __fmul_rn(v0, v0), p1 = __fmul_rn(v1, v1);
        float p2 = __fmul_rn(v2, v2), p3 = __fmul_rn(v3, v3);
        if (c < 2) { r[j] = p0; r[j+1] = p1; r[j+2] = p2; r[j+3] = p3; }
        else { r[j]   = __fadd_rn(r[j],   p0); r[j+1] = __fadd_rn(r[j+1], p1);
               r[j+2] = __fadd_rn(r[j+2], p2); r[j+3] = __fadd_rn(r[j+3], p3); }
    }
    const float A = tree8(r[0], r[1], r[2], r[3], r[4], r[5], r[6], r[7]);

    // ---- scan my 128-code group (pure s_load + FMA loop)
    float best  = INFINITY;
    int   bestk = 0;
    for (int kk = 0; kk < KPG; ++kk) {
        const int k = g * KPG + kk;             // wave-uniform -> s_load path
        const float* wk = w + (size_t)k * DIM;
        float s[8];
        #pragma unroll
        for (int c = 0; c < 16; ++c) {
            const int j = (c & 1) * 4;
            const float* wc = wk + 4 * c;
            if (c < 2) {
                s[j]   = __fmul_rn(x2[c].x, wc[0]);           // == fmaf(a,b,0)
                s[j+1] = __fmul_rn(x2[c].y, wc[1]);
                s[j+2] = __fmul_rn(x2[c].z, wc[2]);
                s[j+3] = __fmul_rn(x2[c].w, wc[3]);
            } else {
                s[j]   = __fmaf_rn(x2[c].x, wc[0], s[j]);
                s[j+1] = __fmaf_rn(x2[c].y, wc[1], s[j+1]);
                s[j+2] = __fmaf_rn(x2[c].z, wc[2], s[j+2]);
                s[j+3] = __fmaf_rn(x2[c].w, wc[3], s[j+3]);
            }
        }
        float dot  = tree8(s[0], s[1], s[2], s[3], s[4], s[5], s[6], s[7]);
        float t    = __fadd_rn(A, ww[k]);       // (||x||^2 + ||w_k||^2), ref order
        float dist = __fadd_rn(t, -dot);        // minus 2*x.w
        if (dist < best) { best = dist; bestk = k; }
    }
    cdist[g][l] = best;
    ckidx[g][l] = bestk;

    __syncthreads();

    // ---- merge 4 candidates (ascending g = ascending k: ties keep first) ----
    float fb = cdist[0][l];
    int   fk = ckidx[0][l];
    #pragma unroll
    for (int gg = 1; gg < GROUPS; ++gg) {
        float dg = cdist[gg][l];
        int   kg = ckidx[gg][l];
        if (dg < fb) { fb = dg; fk = kg; }
    }

    // ---- epilogue: wave 0 only (constant x2 indices)
    if (g == 0) {
        out[ENC_OFF + (size_t)n * KCODES + fk] = 1.0f;   // zeros already laid by vq_fill
        atomicAdd(&hcount[fk], 1);

        const float4* wrow = reinterpret_cast<const float4*>(w + (size_t)fk * DIM);
        float* qo = out + ((size_t)b * DIM) * HW + hw;
        float sse = 0.0f;
        #pragma unroll
        for (int c = 0; c < 16; ++c) {
            float4 q = wrow[c];
            qo[(size_t)(4 * c + 0) * HW] = q.x;
            qo[(size_t)(4 * c + 1) * HW] = q.y;
            qo[(size_t)(4 * c + 2) * HW] = q.z;
            qo[(size_t)(4 * c + 3) * HW] = q.w;
            float e0 = q.x - 0.5f * x2[c].x; sse = __fmaf_rn(e0, e0, sse);
            float e1 = q.y - 0.5f * x2[c].y; sse = __fmaf_rn(e1, e1, sse);
            float e2 = q.z - 0.5f * x2[c].z; sse = __fmaf_rn(e2, e2, sse);
            float e3 = q.w - 0.5f * x2[c].w; sse = __fmaf_rn(e3, e3, sse);
        }
        // wave-level SSE reduction (64 lanes)
        #pragma unroll
        for (int off = 32; off > 0; off >>= 1) sse += __shfl_down(sse, off);
        if (l == 0) atomicAdd(lossAcc, sse);
    }

    __syncthreads();   // wave 0's hcount atomics done

    // histogram drain
    {
        int c0 = hcount[tid];       if (c0) atomicAdd(&counts[tid], c0);
        int c1 = hcount[tid + TB];  if (c1) atomicAdd(&counts[tid + TB], c1);
    }
}

// Finalize: loss scalar + perplexity from histogram.
extern "C" __global__ __launch_bounds__(512)
void vq_finalize(const int* __restrict__ counts, const float* __restrict__ lossAcc,
                 float* __restrict__ out)
{
    __shared__ double sred[KCODES];
    const int t = threadIdx.x;                 // 512 threads
    double p = (double)counts[t] * (1.0 / (double)NPOS);
    sred[t] = -p * log(p + 1e-10);
    __syncthreads();
    for (int s = KCODES / 2; s > 0; s >>= 1) {
        if (t < s) sred[t] += sred[t + s];
        __syncthreads();
    }
    if (t == 0) {
        out[PERP_OFF] = (float)exp(sred[0]);
        out[LOSS_OFF] = 1.25f * (lossAcc[0] / 8388608.0f);
    }
}

extern "C" void kernel_launch(void* const* d_in, const int* in_sizes, int n_in,
                              void* d_out, int out_size, void* d_ws, size_t ws_size,
                              hipStream_t stream)
{
    const float* x = (const float*)d_in[0];    // [32,64,64,64] fp32
    const float* w = (const float*)d_in[1];    // [512,64] fp32
    float* out = (float*)d_out;

    float* ww      = (float*)d_ws;                         // 512 floats
    int*   counts  = (int*)((char*)d_ws + 2048);           // 512 ints
    float* lossAcc = (float*)((char*)d_ws + 4096);         // 1 float

    vq_prep<<<1, 512, 0, stream>>>(w, ww, counts, lossAcc);
    vq_fill<<<8192, 256, 0, stream>>>(out);
    vq_scan<<<NPOS / POSB, TB, 0, stream>>>(x, w, ww, out, counts, lossAcc);
    vq_finalize<<<1, 512, 0, stream>>>(counts, lossAcc, out);
}

// Round 9
// 520.863 us; speedup vs baseline: 1.0716x; 1.0716x over previous
//
#include <hip/hip_runtime.h>
#include <math.h>

// ---- problem constants ----
#define TB        256           // threads per block = 4 waves (compute kernel)
#define POSB      64            // positions per block (1 per lane)
#define GROUPS    4             // K-split: wave g scans codes [g*KPG,(g+1)*KPG)
#define KPG       128           // codes per group
#define NPOS      131072        // B*H*W positions
#define KCODES    512
#define DIM       64
#define HW        4096          // H*W
#define LOSS_OFF  8388608ull
#define ENC_OFF   8388609ull    // encodings: 67108864 dwords, ends at 75497473
#define PERP_OFF  75497473ull
#define ENC_LEN   67108864ull
#define PADN      8960          // LDS pad: 35840 B -> total ~39.9 KB -> 4 blocks/CU

__device__ __forceinline__ float tree8(float r0, float r1, float r2, float r3,
                                       float r4, float r5, float r6, float r7) {
    // numpy pairwise combine: ((r0+r1)+(r2+r3)) + ((r4+r5)+(r6+r7))
    return __fadd_rn(__fadd_rn(__fadd_rn(r0, r1), __fadd_rn(r2, r3)),
                     __fadd_rn(__fadd_rn(r4, r5), __fadd_rn(r6, r7)));
}

// Prep: ww[k] = sum(w[k]^2) in numpy pairwise order; zero counts + loss accumulator.
extern "C" __global__ __launch_bounds__(512)
void vq_prep(const float* __restrict__ w, float* __restrict__ ww,
             int* __restrict__ counts, float* __restrict__ lossAcc)
{
    const int k = threadIdx.x;                 // 512 threads
    const float* wk = w + k * DIM;
    float r[8];
    #pragma unroll
    for (int i = 0; i < 8; ++i) {
        #pragma unroll
        for (int j = 0; j < 8; ++j) {
            float v = wk[i * 8 + j];
            float pp = __fmul_rn(v, v);
            r[j] = (i == 0) ? pp : __fadd_rn(r[j], pp);
        }
    }
    ww[k] = tree8(r[0], r[1], r[2], r[3], r[4], r[5], r[6], r[7]);
    counts[k] = 0;
    if (k == 0) *lossAcc = 0.0f;
}

// Kernel A: pure zero-fill of the encodings region, rocclr-fill shape
// (8192 blocks x 256 thr x 8 float4, block-contiguous -> coalesced).
// Region starts at odd dword ENC_OFF: 3 head dwords + 16777215 float4 + 1 tail.
extern "C" __global__ __launch_bounds__(256)
void vq_fill(float* __restrict__ out)
{
    const float4 zero4 = make_float4(0.0f, 0.0f, 0.0f, 0.0f);
    float4* dst = reinterpret_cast<float4*>(out + ENC_OFF + 3);   // 16B-aligned
    const size_t base = (size_t)blockIdx.x * (256 * 8) + threadIdx.x;
    #pragma unroll
    for (int i = 0; i < 8; ++i) {
        const size_t m = base + (size_t)i * 256;
        if (m < 16777215ull) dst[m] = zero4;
    }
    if (blockIdx.x == 0 && threadIdx.x < 4) {
        // head dwords ENC_OFF..ENC_OFF+2 and tail dword ENC_OFF+ENC_LEN-1
        const size_t d = (threadIdx.x < 3) ? (ENC_OFF + threadIdx.x)
                                           : (ENC_OFF + ENC_LEN - 1);
        out[d] = 0.0f;
    }
}

// Kernel B, R9: R8 scan + LDS pad to force the register allocator's hand.
// ALLOCATOR MODEL (fits R1-R8): occupancy target = f(workgroup size, STATIC
// LDS) only; launch_bounds min-waves and amdgpu_waves_per_eu are IGNORED.
// TB=256 + 4KB LDS -> target 8 waves/EU -> budget 64 -> x2 spilled (VGPR=56,
// 207-240us). With ~40KB LDS: 4 blocks/CU -> target 4 waves/EU -> budget 128
// >= ~105 needed -> x2[16] stays in VGPRs. 4 waves/EU also hides the per-iter
// SMEM batch wait (VALU demand 616cyc > 414cyc wall) -> VALU-bound scan.
extern "C" __global__ __launch_bounds__(TB)
void vq_scan(const float* __restrict__ x, const float* __restrict__ w,
             const float* __restrict__ ww, float* __restrict__ out,
             int* __restrict__ counts, float* __restrict__ lossAcc)
{
    __shared__ float cdist[GROUPS][POSB];
    __shared__ int   ckidx[GROUPS][POSB];
    __shared__ int   hcount[KCODES];
    __shared__ float pad[PADN];     // occupancy shaper; kept alive below

    const int tid = threadIdx.x;
    const int l   = tid & 63;                                  // lane = position slot
    const int g   = __builtin_amdgcn_readfirstlane(tid >> 6);  // wave id, uniform
    const int n   = blockIdx.x * POSB + l;                     // position (64|4096: one b per block)
    const int b   = n >> 12;
    const int hw  = n & 4095;

    hcount[tid]      = 0;
    hcount[tid + TB] = 0;
    pad[tid] = 0.0f;                // touch so the array isn't dead

    // ---- prologue: x into VGPRs (channel stride HW) as 16 float4 of 2x, and
    // A = sum(x^2) replicating numpy pairwise_sum(64): r[j] over i ascending,
    // chunk c -> (i = c>>1, j = (c&1)*4+e).
    const float* xp = x + ((size_t)b * DIM) * HW + hw;
    float4 x2[16];
    float r[8];
    #pragma unroll
    for (int c = 0; c < 16; ++c) {
        float v0 = xp[(size_t)(4 * c + 0) * HW];
        float v1 = xp[(size_t)(4 * c + 1) * HW];
        float v2 = xp[(size_t)(4 * c + 2) * HW];
        float v3 = xp[(size_t)(4 * c + 3) * HW];
        x2[c].x = v0 + v0; x2[c].y = v1 + v1;       // exact doubling
        x2[c].z = v2 + v2; x2[c].w = v3 + v3;
        const int j = (c & 1) * 4;
        float p0 = __fmul_rn(v0, v0), p1 = __fmul_rn(v1, v1);
        float p2 = __fmul_rn(v2, v2), p3 = __fmul_rn(v3, v3);
        if (c < 2) { r[j] = p0; r[j+1] = p1; r[j+2] = p2; r[j+3] = p3; }
        else { r[j]   = __fadd_rn(r[j],   p0); r[j+1] = __fadd_rn(r[j+1], p1);
               r[j+2] = __fadd_rn(r[j+2], p2); r[j+3] = __fadd_rn(r[j+3], p3); }
    }
    const float A = tree8(r[0], r[1], r[2], r[3], r[4], r[5], r[6], r[7]);

    // ---- scan my 128-code group (pure s_load + FMA loop)
    float best  = INFINITY;
    int   bestk = 0;
    for (int kk = 0; kk < KPG; ++kk) {
        const int k = g * KPG + kk;             // wave-uniform -> s_load path
        const float* wk = w + (size_t)k * DIM;
        float s[8];
        #pragma unroll
        for (int c = 0; c < 16; ++c) {
            const int j = (c & 1) * 4;
            const float* wc = wk + 4 * c;
            if (c < 2) {
                s[j]   = __fmul_rn(x2[c].x, wc[0]);           // == fmaf(a,b,0)
                s[j+1] = __fmul_rn(x2[c].y, wc[1]);
                s[j+2] = __fmul_rn(x2[c].z, wc[2]);
                s[j+3] = __fmul_rn(x2[c].w, wc[3]);
            } else {
                s[j]   = __fmaf_rn(x2[c].x, wc[0], s[j]);
                s[j+1] = __fmaf_rn(x2[c].y, wc[1], s[j+1]);
                s[j+2] = __fmaf_rn(x2[c].z, wc[2], s[j+2]);
                s[j+3] = __fmaf_rn(x2[c].w, wc[3], s[j+3]);
            }
        }
        float dot  = tree8(s[0], s[1], s[2], s[3], s[4], s[5], s[6], s[7]);
        float t    = __fadd_rn(A, ww[k]);       // (||x||^2 + ||w_k||^2), ref order
        float dist = __fadd_rn(t, -dot);        // minus 2*x.w
        if (dist < best) { best = dist; bestk = k; }
    }
    cdist[g][l] = best;
    ckidx[g][l] = bestk;

    __syncthreads();

    // ---- merge 4 candidates (ascending g = ascending k: ties keep first) ----
    float fb = cdist[0][l];
    int   fk = ckidx[0][l];
    #pragma unroll
    for (int gg = 1; gg < GROUPS; ++gg) {
        float dg = cdist[gg][l];
        int   kg = ckidx[gg][l];
        if (dg < fb) { fb = dg; fk = kg; }
    }

    // keep pad alive: fk is always in [0,512), so this never executes,
    // but the compiler cannot prove it -> pad counts toward static LDS.
    if (fk < 0) atomicAdd(lossAcc, pad[tid]);

    // ---- epilogue: wave 0 only (constant x2 indices)
    if (g == 0) {
        out[ENC_OFF + (size_t)n * KCODES + fk] = 1.0f;   // zeros already laid by vq_fill
        atomicAdd(&hcount[fk], 1);

        const float4* wrow = reinterpret_cast<const float4*>(w + (size_t)fk * DIM);
        float* qo = out + ((size_t)b * DIM) * HW + hw;
        float sse = 0.0f;
        #pragma unroll
        for (int c = 0; c < 16; ++c) {
            float4 q = wrow[c];
            qo[(size_t)(4 * c + 0) * HW] = q.x;
            qo[(size_t)(4 * c + 1) * HW] = q.y;
            qo[(size_t)(4 * c + 2) * HW] = q.z;
            qo[(size_t)(4 * c + 3) * HW] = q.w;
            float e0 = q.x - 0.5f * x2[c].x; sse = __fmaf_rn(e0, e0, sse);
            float e1 = q.y - 0.5f * x2[c].y; sse = __fmaf_rn(e1, e1, sse);
            float e2 = q.z - 0.5f * x2[c].z; sse = __fmaf_rn(e2, e2, sse);
            float e3 = q.w - 0.5f * x2[c].w; sse = __fmaf_rn(e3, e3, sse);
        }
        // wave-level SSE reduction (64 lanes)
        #pragma unroll
        for (int off = 32; off > 0; off >>= 1) sse += __shfl_down(sse, off);
        if (l == 0) atomicAdd(lossAcc, sse);
    }

    __syncthreads();   // wave 0's hcount atomics done

    // histogram drain
    {
        int c0 = hcount[tid];       if (c0) atomicAdd(&counts[tid], c0);
        int c1 = hcount[tid + TB];  if (c1) atomicAdd(&counts[tid + TB], c1);
    }
}

// Finalize: loss scalar + perplexity from histogram.
extern "C" __global__ __launch_bounds__(512)
void vq_finalize(const int* __restrict__ counts, const float* __restrict__ lossAcc,
                 float* __restrict__ out)
{
    __shared__ double sred[KCODES];
    const int t = threadIdx.x;                 // 512 threads
    double p = (double)counts[t] * (1.0 / (double)NPOS);
    sred[t] = -p * log(p + 1e-10);
    __syncthreads();
    for (int s = KCODES / 2; s > 0; s >>= 1) {
        if (t < s) sred[t] += sred[t + s];
        __syncthreads();
    }
    if (t == 0) {
        out[PERP_OFF] = (float)exp(sred[0]);
        out[LOSS_OFF] = 1.25f * (lossAcc[0] / 8388608.0f);
    }
}

extern "C" void kernel_launch(void* const* d_in, const int* in_sizes, int n_in,
                              void* d_out, int out_size, void* d_ws, size_t ws_size,
                              hipStream_t stream)
{
    const float* x = (const float*)d_in[0];    // [32,64,64,64] fp32
    const float* w = (const float*)d_in[1];    // [512,64] fp32
    float* out = (float*)d_out;

    float* ww      = (float*)d_ws;                         // 512 floats
    int*   counts  = (int*)((char*)d_ws + 2048);           // 512 ints
    float* lossAcc = (float*)((char*)d_ws + 4096);         // 1 float

    vq_prep<<<1, 512, 0, stream>>>(w, ww, counts, lossAcc);
    vq_fill<<<8192, 256, 0, stream>>>(out);
    vq_scan<<<NPOS / POSB, TB, 0, stream>>>(x, w, ww, out, counts, lossAcc);
    vq_finalize<<<1, 512, 0, stream>>>(counts, lossAcc, out);
}